// Round 1
// baseline (1319.432 us; speedup 1.0000x reference)
//
#include <hip/hip_runtime.h>
#include <cstdint>
#include <cstddef>

// BooleanReservoir: batch-bit-packed boolean reservoir.
// lane = batch (64 lanes = 64 batches). states[node] = u64, bit b = state of batch b.
// Per step: node waves gather 12 neighbor words, build per-lane 12-bit LUT index,
// gather packed LUT word, ballot -> new packed state. 128 stream-ordered launches
// provide the inter-step grid sync + cross-XCD coherence.

#define N_NODES   20000
#define N_INPUT   64
#define K_MAX     12
#define T_STEPS   128
#define N_BATCH   64
#define N_OUT     10
#define N_FEAT    (N_NODES - N_INPUT)   // 19936
#define DUMMY_NODE 20000                // always-zero state word (masked neighbors)
#define ST_WORDS  20004                 // states buffer incl. dummy + pad

typedef unsigned long long u64;

// Node waves: 19936 nodes, 5 per wave -> 3987 full waves + 1 (gw 3987 has 1 node).
#define NODE_WAVES 3988
#define U_WAVE     3999
#define STEP_BLOCKS 1000                // 4000 waves

// ---------------- pack x: xp[t][b] = bits j of x[b][t][j] ----------------
__global__ __launch_bounds__(256) void pack_x_kernel(const int* __restrict__ x,
                                                     u64* __restrict__ xp) {
  const int t = blockIdx.x;
  const int wave = threadIdx.x >> 6, lane = threadIdx.x & 63;
  for (int b = wave; b < N_BATCH; b += 4) {
    int v = x[((size_t)b * T_STEPS + t) * 64 + lane];   // coalesced 64 ints
    u64 bal = __ballot(v != 0);
    if (lane == 0) xp[(size_t)t * N_BATCH + b] = bal;
  }
}

// ------------- pack lut (bitmask words) + masked adj + has-neighbor -------------
__global__ __launch_bounds__(256) void pack_lut_kernel(const int* __restrict__ lut,
                                                       const int* __restrict__ adj,
                                                       const int* __restrict__ mask,
                                                       u64* __restrict__ lutp,
                                                       int* __restrict__ adj2,
                                                       unsigned char* __restrict__ hn) {
  const int n = blockIdx.x;
  const int wave = threadIdx.x >> 6, lane = threadIdx.x & 63;
  const int* L = lut + (size_t)n * 4096;
  for (int w = wave; w < 64; w += 4) {
    int v = L[(size_t)w * 64 + lane];                    // coalesced 256B
    u64 bal = __ballot(v != 0);                          // bit lane = entry w*64+lane
    if (lane == 0) lutp[(size_t)n * 64 + w] = bal;
  }
  if (wave == 0) {
    int a = DUMMY_NODE, m = 0;
    if (lane < K_MAX) {
      a = adj[(size_t)n * K_MAX + lane];
      m = mask[(size_t)n * K_MAX + lane];
    }
    u64 anym = __ballot(lane < K_MAX && m != 0);
    if (lane < K_MAX) adj2[(size_t)n * K_MAX + lane] = (m != 0) ? a : DUMMY_NODE;
    if (lane == 0) hn[n] = (anym != 0) ? 1 : 0;
  }
}

// -------- init both state buffers (nodes >= N_INPUT + dummy), wcol, u(0) --------
__global__ __launch_bounds__(256) void init_kernel(const int* __restrict__ inis,
                                                   const int* __restrict__ w_in,
                                                   const u64* __restrict__ xp,
                                                   u64* __restrict__ buf0,
                                                   u64* __restrict__ buf1,
                                                   u64* __restrict__ wcol) {
  if (blockIdx.x < 79) {
    int n = blockIdx.x * 256 + threadIdx.x;
    if (n >= N_INPUT && n < ST_WORDS) {
      u64 w = (n < N_NODES && inis[n] != 0) ? ~0ull : 0ull;   // dummy/pad -> 0
      buf0[n] = w;
      buf1[n] = w;   // no-neigh nodes never rewritten: init must live in both buffers
    }
  } else {
    // block 79: wcol[i] = bits j of w_in[j][i]; then u(0) -> buf0[0..63]
    const int wave = threadIdx.x >> 6, lane = threadIdx.x & 63;
    u64 xw = xp[lane];                       // xp[t=0][b=lane]
    for (int i = wave; i < 64; i += 4) {
      int wv = w_in[(size_t)lane * 64 + i];  // lane = j
      u64 wc = __ballot(wv != 0);            // uniform across wave
      if (lane == 0) wcol[i] = wc;
      u64 ub = __ballot((xw & wc) != 0);     // u(0)[b][i], lane = b
      if (lane == 0) buf0[i] = ub;
    }
  }
}

// ---------------- one timestep ----------------
__global__ __launch_bounds__(256) void step_kernel(const u64* __restrict__ cur,
                                                   u64* __restrict__ nxt,
                                                   const int* __restrict__ adj2,
                                                   const unsigned char* __restrict__ hn,
                                                   const u64* __restrict__ lutp,
                                                   const u64* __restrict__ xp,
                                                   const u64* __restrict__ wcol,
                                                   int t) {
  __shared__ u64 scratch[4][64];
  const int wave = threadIdx.x >> 6, lane = threadIdx.x & 63;
  const int gw = blockIdx.x * 4 + wave;

  if (gw < NODE_WAVES) {
    const int n0 = N_INPUT + gw * 5;
    const int cnt = min(5, N_NODES - n0);
    const int na = cnt * K_MAX;

    // gather phase: lane l -> neighbor word for (node l/12, slot l%12)
    u64 stv = 0;
    if (lane < na) {
      int a = adj2[(size_t)n0 * K_MAX + lane];   // coalesced
      stv = cur[a];                              // random gather (L2/L3)
    }
    scratch[wave][lane] = stv;                   // wave-internal, no barrier needed

    // compute phase: lane = batch; build 12-bit index per (node, batch), issue LUT gathers
    unsigned idx[5];
    u64 g[5];
#pragma unroll
    for (int i = 0; i < 5; i++) {
      if (i < cnt) {
        unsigned v = 0;
#pragma unroll
        for (int j = 0; j < K_MAX; j++) {
          u64 w = scratch[wave][i * K_MAX + j];  // broadcast read
          v = (v << 1) | (unsigned)((w >> lane) & 1ull);   // MSB-first: j=0 -> bit 11
        }
        idx[i] = v;
        g[i] = lutp[(size_t)(n0 + i) * 64 + (v >> 6)];     // 4 lines per node
      }
    }
#pragma unroll
    for (int i = 0; i < 5; i++) {
      if (i < cnt) {
        u64 nb = __ballot((unsigned)((g[i] >> (idx[i] & 63)) & 1ull));
        if (lane == 0 && hn[n0 + i]) nxt[n0 + i] = nb;     // no-neigh: keep (skip write)
      }
    }
  } else if (gw == U_WAVE) {
    // compute u(t+1) into nxt[0..63] for next step's gathers
    if (t + 1 < T_STEPS) {
      u64 xw = xp[(size_t)(t + 1) * N_BATCH + lane];       // lane = batch
      for (int i = 0; i < 64; i++) {
        u64 wc = wcol[i];
        u64 ub = __ballot((xw & wc) != 0);
        if (lane == 0) nxt[i] = ub;
      }
    }
  }
}

// ---------------- readout: sigmoid(feats @ W_out^T + b_out) ----------------
__global__ __launch_bounds__(256) void readout_kernel(const u64* __restrict__ st,
                                                      const float* __restrict__ Wout,
                                                      const float* __restrict__ bout,
                                                      float* __restrict__ out) {
  const int b = blockIdx.x / N_OUT;
  const int o = blockIdx.x % N_OUT;
  float acc = 0.f;
  for (int n = threadIdx.x; n < N_FEAT; n += 256) {
    u64 s = st[N_INPUT + n];                 // coalesced 8B
    float w = Wout[(size_t)o * N_FEAT + n];  // coalesced 4B
    acc += ((s >> b) & 1ull) ? w : 0.f;
  }
  for (int off = 32; off > 0; off >>= 1) acc += __shfl_down(acc, off);
  __shared__ float red[4];
  const int wave = threadIdx.x >> 6, lane = threadIdx.x & 63;
  if (lane == 0) red[wave] = acc;
  __syncthreads();
  if (threadIdx.x == 0) {
    float tot = red[0] + red[1] + red[2] + red[3] + bout[o];
    out[(size_t)b * N_OUT + o] = 1.f / (1.f + __expf(-tot));
  }
}

extern "C" void kernel_launch(void* const* d_in, const int* in_sizes, int n_in,
                              void* d_out, int out_size, void* d_ws, size_t ws_size,
                              hipStream_t stream) {
  const int* x    = (const int*)d_in[0];
  const int* w_in = (const int*)d_in[1];
  const int* adj  = (const int*)d_in[2];
  const int* mask = (const int*)d_in[3];
  const int* lut  = (const int*)d_in[4];
  const int* inis = (const int*)d_in[5];
  const float* Wout = (const float*)d_in[6];
  const float* bout = (const float*)d_in[7];
  float* out = (float*)d_out;

  char* ws = (char*)d_ws;
  size_t off = 0;
  auto alloc = [&](size_t bytes) -> void* {
    void* p = ws + off;
    off += (bytes + 255) & ~(size_t)255;
    return p;
  };
  u64* buf0 = (u64*)alloc((size_t)ST_WORDS * 8);
  u64* buf1 = (u64*)alloc((size_t)ST_WORDS * 8);
  u64* lutp = (u64*)alloc((size_t)N_NODES * 64 * 8);          // 10.24 MB
  u64* xp   = (u64*)alloc((size_t)T_STEPS * N_BATCH * 8);
  u64* wcol = (u64*)alloc(64 * 8);
  int* adj2 = (int*)alloc((size_t)N_NODES * K_MAX * 4);
  unsigned char* hn = (unsigned char*)alloc(N_NODES);
  (void)ws_size; (void)in_sizes; (void)n_in; (void)out_size;

  hipLaunchKernelGGL(pack_x_kernel, dim3(T_STEPS), dim3(256), 0, stream, x, xp);
  hipLaunchKernelGGL(pack_lut_kernel, dim3(N_NODES), dim3(256), 0, stream,
                     lut, adj, mask, lutp, adj2, hn);
  hipLaunchKernelGGL(init_kernel, dim3(80), dim3(256), 0, stream,
                     inis, w_in, xp, buf0, buf1, wcol);

  for (int t = 0; t < T_STEPS; t++) {
    const u64* cur = (t & 1) ? buf1 : buf0;
    u64* nxt       = (t & 1) ? buf0 : buf1;
    hipLaunchKernelGGL(step_kernel, dim3(STEP_BLOCKS), dim3(256), 0, stream,
                       cur, nxt, adj2, hn, lutp, xp, wcol, t);
  }
  // T even -> final states in buf0
  hipLaunchKernelGGL(readout_kernel, dim3(N_BATCH * N_OUT), dim3(256), 0, stream,
                     buf0, Wout, bout, out);
}